// Round 5
// baseline (565.217 us; speedup 1.0000x reference)
//
#include <hip/hip_runtime.h>
#include <hip/hip_bf16.h>
#include <math.h>

#define N_PTS 8192
#define QPB 4            // queries per block = waves per block

// F_CHAMFER*ALPHA0 = 0.02, F_CURVATURE*ALPHA0 = 0.006, F_SMOOTH*ALPHA0 = 0.01
#define W_CHAM 0.02f
#define W_CURV 0.006f
#define W_SMOO 0.01f

#define BIGF 1e30f

// ---- wave-uniform sorted insert (used only on the rare fallback path) ----
template <int K>
__device__ __forceinline__ void uinsert(float d, int idx, float (&bd)[K], int (&bi)[K]) {
    bd[K - 1] = d; bi[K - 1] = idx;
#pragma unroll
    for (int s = K - 1; s > 0; --s) {
        bool sw = bd[s] < bd[s - 1];
        float td = sw ? bd[s - 1] : bd[s];
        bd[s - 1] = sw ? bd[s] : bd[s - 1];
        bd[s] = td;
        int ti = sw ? bi[s - 1] : bi[s];
        bi[s - 1] = sw ? bi[s] : bi[s - 1];
        bi[s] = ti;
    }
}

// ---- exact top-K: branchless per-lane top-3 direct-from-global scan ----
// cand: float4 SoA-packed points (x,y,z,pad). No LDS, no barriers.
// Result bd/bi wave-uniform.
template <int K>
__device__ void knn_scan(const float4* __restrict__ cand,
                         float qx, float qy, float qz,
                         float (&bd)[K], int (&bi)[K], int lane) {
    float m1 = BIGF, m2 = BIGF, m3 = BIGF;
    int   i1 = 0,    i2 = 0;
#pragma unroll 8
    for (int base = 0; base < N_PTS; base += 64) {
        const int idx = base + lane;
        float4 p = cand[idx];
        float dx = p.x - qx, dy = p.y - qy, dz = p.z - qz;
        float d = dx * dx + dy * dy + dz * dz;
        bool c1 = d < m1, c2 = d < m2, c3 = d < m3;
        m3 = c2 ? m2 : (c3 ? d : m3);
        m2 = c1 ? m1 : (c2 ? d : m2);
        i2 = c1 ? i1 : (c2 ? idx : i2);
        m1 = c1 ? d : m1;
        i1 = c1 ? idx : i1;
    }

    // merge 64 sorted 3-lists (3rd entry has no index -> sentinel -1)
    float h0 = m1, h1 = m2, h2 = m3;
    int   j0 = i1, j1 = i2, j2 = -1;
#pragma unroll
    for (int r = 0; r < K; ++r) {
        float bv = h0; int bix = j0; int bl = lane;
#pragma unroll
        for (int off = 1; off < 64; off <<= 1) {
            float ov  = __shfl_xor(bv, off);
            int   oix = __shfl_xor(bix, off);
            int   ol  = __shfl_xor(bl, off);
            if (ov < bv || (ov == bv && ol < bl)) { bv = ov; bix = oix; bl = ol; }
        }
        bd[r] = bv; bi[r] = bix;
        if (lane == bl) { h0 = h1; j0 = j1; h1 = h2; j1 = j2; h2 = BIGF; j2 = -1; }
    }

    // certificate: every lane's unreported candidates are >= its m3.
    if (__ballot(m3 <= bd[K - 1]) != 0ull) {
        // rare exact fallback (no barriers -> divergence-safe)
#pragma unroll
        for (int r = 0; r < K; ++r) { bd[r] = BIGF; bi[r] = 0; }
        for (int base = 0; base < N_PTS; base += 64) {
            const int j = base + lane;
            float4 p = cand[j];
            float dx = p.x - qx, dy = p.y - qy, dz = p.z - qz;
            float d = dx * dx + dy * dy + dz * dz;
            unsigned long long m = __ballot(d < bd[K - 1]);
            while (m) {
                int b = __builtin_ctzll(m);
                m &= m - 1;
                float dv = __shfl(d, b);
                if (dv < bd[K - 1]) uinsert<K>(dv, base + b, bd, bi);
            }
        }
    }
}

// ---- kernel 0: build pc2/warp (AoS + packed float4), zero accumulators ----
__global__ void prep_kernel(const float* __restrict__ flow, const float* __restrict__ gt,
                            const float* __restrict__ coords,
                            float* __restrict__ pc2, float* __restrict__ warp,
                            float4* __restrict__ p1q, float4* __restrict__ p2q,
                            float4* __restrict__ wq, float* __restrict__ accs) {
    int i = blockIdx.x * blockDim.x + threadIdx.x;
    if (i < N_PTS) {
        float cx = coords[3 * i + 0], cy = coords[3 * i + 1], cz = coords[3 * i + 2];
        float p2x = cx + gt[3 * i + 0], p2y = cy + gt[3 * i + 1], p2z = cz + gt[3 * i + 2];
        float wx = cx + flow[3 * i + 0], wy = cy + flow[3 * i + 1], wz = cz + flow[3 * i + 2];
        pc2[3 * i + 0] = p2x; pc2[3 * i + 1] = p2y; pc2[3 * i + 2] = p2z;
        warp[3 * i + 0] = wx; warp[3 * i + 1] = wy; warp[3 * i + 2] = wz;
        p1q[i] = make_float4(cx, cy, cz, 0.f);
        p2q[i] = make_float4(p2x, p2y, p2z, 0.f);
        wq[i]  = make_float4(wx, wy, wz, 0.f);
    }
    if (i < 8) accs[i] = 0.0f;
}

// ---- kernel 1: curvature of pc2 via kNN(pc2,pc2,10) ----
__global__ __launch_bounds__(256) void curv2_kernel(const float4* __restrict__ p2q,
                                                    float* __restrict__ curv2) {
    const int tid = threadIdx.x, lane = tid & 63, wv = tid >> 6;
    const int q = blockIdx.x * QPB + wv;
    float4 qp = p2q[q];
    const float qx = qp.x, qy = qp.y, qz = qp.z;
    constexpr int K = 10;
    float bd[K]; int bi[K];
    knn_scan<K>(p2q, qx, qy, qz, bd, bi, lane);
    float ax = 0.f, ay = 0.f, az = 0.f;
#pragma unroll
    for (int r = 0; r < K; ++r) {
        float4 nb = p2q[bi[r]];
        ax += nb.x; ay += nb.y; az += nb.z;
    }
    if (lane == 0) {
        curv2[q * 3 + 0] = (ax - 10.f * qx) * (1.f / 9.f);
        curv2[q * 3 + 1] = (ay - 10.f * qy) * (1.f / 9.f);
        curv2[q * 3 + 2] = (az - 10.f * qz) * (1.f / 9.f);
    }
}

// ---- kernel 2: kNN(pc1,pc1,10) -> moved_curv + smoothness ----
__global__ __launch_bounds__(256) void pc1_kernel(const float4* __restrict__ p1q,
                                                  const float4* __restrict__ wq,
                                                  const float* __restrict__ flow,
                                                  const int* __restrict__ ksm_p,
                                                  float* __restrict__ mcurv,
                                                  float* __restrict__ accs) {
    __shared__ float psm[QPB];
    const int tid = threadIdx.x, lane = tid & 63, wv = tid >> 6;
    const int q = blockIdx.x * QPB + wv;
    float4 qp = p1q[q];
    const float qx = qp.x, qy = qp.y, qz = qp.z;
    constexpr int K = 10;
    float bd[K]; int bi[K];
    knn_scan<K>(p1q, qx, qy, qz, bd, bi, lane);

    float4 wqp = wq[q];
    const float fqx = flow[q * 3 + 0], fqy = flow[q * 3 + 1], fqz = flow[q * 3 + 2];
    const int ksm = ksm_p[0];  // 9
    float ax = 0.f, ay = 0.f, az = 0.f, sm = 0.f;
#pragma unroll
    for (int r = 0; r < K; ++r) {
        float4 nb = wq[bi[r]];
        ax += nb.x; ay += nb.y; az += nb.z;
        if (r < ksm) {
            float dx = flow[bi[r] * 3 + 0] - fqx;
            float dy = flow[bi[r] * 3 + 1] - fqy;
            float dz = flow[bi[r] * 3 + 2] - fqz;
            float sq = dx * dx + dy * dy + dz * dz;
            sm += (sq == 0.f) ? 0.f : sqrtf(sq);
        }
    }
    if (lane == 0) {
        mcurv[q * 3 + 0] = (ax - 10.f * wqp.x) * (1.f / 9.f);
        mcurv[q * 3 + 1] = (ay - 10.f * wqp.y) * (1.f / 9.f);
        mcurv[q * 3 + 2] = (az - 10.f * wqp.z) * (1.f / 9.f);
        psm[wv] = sm * 0.125f;  // /8.0 hard-coded in reference
    }
    __syncthreads();
    if (tid == 0) atomicAdd(&accs[2], psm[0] + psm[1] + psm[2] + psm[3]);
}

// ---- kernel 3: kNN(warp->pc2,5) -> chamfer dist1 + curvature-interp loss ----
__global__ __launch_bounds__(256) void cross_kernel(const float4* __restrict__ wq,
                                                    const float4* __restrict__ p2q,
                                                    const float* __restrict__ curv2,
                                                    const float* __restrict__ mcurv,
                                                    float* __restrict__ accs) {
    __shared__ float pc1s[QPB], pcvs[QPB];
    const int tid = threadIdx.x, lane = tid & 63, wv = tid >> 6;
    const int q = blockIdx.x * QPB + wv;
    float4 qp = wq[q];
    const float qx = qp.x, qy = qp.y, qz = qp.z;
    constexpr int K = 5;
    float bd[K]; int bi[K];
    knn_scan<K>(p2q, qx, qy, qz, bd, bi, lane);

    float w[K], wsum = 0.f;
#pragma unroll
    for (int r = 0; r < K; ++r) { w[r] = 1.f / (bd[r] + 1e-8f); wsum += w[r]; }
    float ix = 0.f, iy = 0.f, iz = 0.f;
#pragma unroll
    for (int r = 0; r < K; ++r) {
        float ww = w[r] / wsum;
        ix += ww * curv2[bi[r] * 3 + 0];
        iy += ww * curv2[bi[r] * 3 + 1];
        iz += ww * curv2[bi[r] * 3 + 2];
    }
    float dx = ix - mcurv[q * 3 + 0];
    float dy = iy - mcurv[q * 3 + 1];
    float dz = iz - mcurv[q * 3 + 2];
    if (lane == 0) {
        pc1s[wv] = bd[0];                       // dist1 (min)
        pcvs[wv] = dx * dx + dy * dy + dz * dz; // curvature term
    }
    __syncthreads();
    if (tid == 0) {
        atomicAdd(&accs[0], pc1s[0] + pc1s[1] + pc1s[2] + pc1s[3]);
        atomicAdd(&accs[3], pcvs[0] + pcvs[1] + pcvs[2] + pcvs[3]);
    }
}

// ---- kernel 4: reverse chamfer: min over warp for each pc2 point ----
__global__ __launch_bounds__(256) void rev_kernel(const float4* __restrict__ p2q,
                                                  const float4* __restrict__ wq,
                                                  float* __restrict__ accs) {
    __shared__ float pmn[QPB];
    const int tid = threadIdx.x, lane = tid & 63, wv = tid >> 6;
    const int q = blockIdx.x * QPB + wv;
    float4 qp = p2q[q];
    const float qx = qp.x, qy = qp.y, qz = qp.z;
    float mny = BIGF;
#pragma unroll 8
    for (int base = 0; base < N_PTS; base += 64) {
        float4 p = wq[base + lane];
        float dx = p.x - qx, dy = p.y - qy, dz = p.z - qz;
        mny = fminf(mny, dx * dx + dy * dy + dz * dz);
    }
#pragma unroll
    for (int off = 1; off < 64; off <<= 1) mny = fminf(mny, __shfl_xor(mny, off));
    if (lane == 0) pmn[wv] = mny;
    __syncthreads();
    if (tid == 0) atomicAdd(&accs[1], pmn[0] + pmn[1] + pmn[2] + pmn[3]);
}

// ---- kernel 5: finalize ----
__global__ void fin_kernel(const float* __restrict__ accs, float* __restrict__ out) {
    if (threadIdx.x == 0 && blockIdx.x == 0)
        out[0] = W_CHAM * (accs[0] + accs[1]) + W_CURV * accs[3] + W_SMOO * accs[2];
}

extern "C" void kernel_launch(void* const* d_in, const int* in_sizes, int n_in,
                              void* d_out, int out_size, void* d_ws, size_t ws_size,
                              hipStream_t stream) {
    const float* flow   = (const float*)d_in[0];  // registration_pred (1,N,3)
    const float* gt     = (const float*)d_in[1];  // registration_gt   (1,N,3)
    const float* coords = (const float*)d_in[2];  // (N,3)
    const int*   ksm    = (const int*)d_in[3];    // smoothness_k (=9)

    float* ws    = (float*)d_ws;
    float* pc2   = ws;                 // 3N
    float* warp  = ws + 3 * N_PTS;     // 3N
    float* curv2 = ws + 6 * N_PTS;     // 3N
    float* mcurv = ws + 9 * N_PTS;     // 3N
    float* accs  = ws + 12 * N_PTS;    // 8 floats (offset 98304)
    float4* p1q  = (float4*)(ws + 12 * N_PTS + 8);   // N float4 (16B-aligned: 393248%16==0)
    float4* p2q  = p1q + N_PTS;
    float4* wq   = p2q + N_PTS;
    float* out   = (float*)d_out;

    prep_kernel<<<(N_PTS + 255) / 256, 256, 0, stream>>>(flow, gt, coords, pc2, warp,
                                                         p1q, p2q, wq, accs);
    curv2_kernel<<<N_PTS / QPB, 256, 0, stream>>>(p2q, curv2);
    pc1_kernel<<<N_PTS / QPB, 256, 0, stream>>>(p1q, wq, flow, ksm, mcurv, accs);
    cross_kernel<<<N_PTS / QPB, 256, 0, stream>>>(wq, p2q, curv2, mcurv, accs);
    rev_kernel<<<N_PTS / QPB, 256, 0, stream>>>(p2q, wq, accs);
    fin_kernel<<<1, 64, 0, stream>>>(accs, out);
}

// Round 6
// 327.571 us; speedup vs baseline: 1.7255x; 1.7255x over previous
//
#include <hip/hip_runtime.h>
#include <hip/hip_bf16.h>
#include <math.h>

#define N_PTS 8192
#define QPB 4            // queries per block = waves per block

// F_CHAMFER*ALPHA0 = 0.02, F_CURVATURE*ALPHA0 = 0.006, F_SMOOTH*ALPHA0 = 0.01
#define W_CHAM 0.02f
#define W_CURV 0.006f
#define W_SMOO 0.01f

#define BIGF 1e30f

// ---- wave-uniform sorted insert (fallback path only; args wave-uniform) ----
template <int K>
__device__ __forceinline__ void uinsert(float d, int idx, float (&bd)[K], int (&bi)[K]) {
    bd[K - 1] = d; bi[K - 1] = idx;
#pragma unroll
    for (int s = K - 1; s > 0; --s) {
        bool sw = bd[s] < bd[s - 1];
        float td = sw ? bd[s - 1] : bd[s];
        bd[s - 1] = sw ? bd[s] : bd[s - 1];
        bd[s] = td;
        int ti = sw ? bi[s - 1] : bi[s];
        bi[s - 1] = sw ? bi[s] : bi[s - 1];
        bi[s] = ti;
    }
}

// ---- exact top-K: branchless per-lane top-3(+m4 certificate) scan ----
// cand: float4-packed points (x,y,z,pad). No LDS, no barriers.
// Result bd/bi wave-uniform and exact.
template <int K>
__device__ void knn_scan(const float4* __restrict__ cand,
                         float qx, float qy, float qz,
                         float (&bd)[K], int (&bi)[K], int lane) {
    float m1 = BIGF, m2 = BIGF, m3 = BIGF, m4 = BIGF;
    int   i1 = 0,    i2 = 0,    i3 = 0;
#pragma unroll 8
    for (int base = 0; base < N_PTS; base += 64) {
        const int idx = base + lane;
        float4 p = cand[idx];
        float dx = p.x - qx, dy = p.y - qy, dz = p.z - qz;
        float d = dx * dx + dy * dy + dz * dz;
        bool c1 = d < m1, c2 = d < m2, c3 = d < m3, c4 = d < m4;
        m4 = c3 ? m3 : (c4 ? d : m4);
        m3 = c2 ? m2 : (c3 ? d : m3);
        i3 = c2 ? i2 : (c3 ? idx : i3);
        m2 = c1 ? m1 : (c2 ? d : m2);
        i2 = c1 ? i1 : (c2 ? idx : i2);
        m1 = c1 ? d : m1;
        i1 = c1 ? idx : i1;
    }

    // merge 64 sorted 3-lists (all three entries carry real indices)
    float h0 = m1, h1 = m2, h2 = m3;
    int   j0 = i1, j1 = i2, j2 = i3;
#pragma unroll
    for (int r = 0; r < K; ++r) {
        float bv = h0; int bix = j0; int bl = lane;
#pragma unroll
        for (int off = 1; off < 64; off <<= 1) {
            float ov  = __shfl_xor(bv, off);
            int   oix = __shfl_xor(bix, off);
            int   ol  = __shfl_xor(bl, off);
            if (ov < bv || (ov == bv && ol < bl)) { bv = ov; bix = oix; bl = ol; }
        }
        bd[r] = bv; bi[r] = bix;
        if (lane == bl) { h0 = h1; j0 = j1; h1 = h2; j1 = j2; h2 = BIGF; j2 = -1; }
    }

    // certificate: unreported candidates of a lane are >= its m4.
    // Fails only if some lane held >=4 of the true top-K: P ~ 0.08% per query.
    if (__ballot(m4 <= bd[K - 1]) != 0ull) {
        // cheap exact fallback: tau = merged bd[K-1] is an UPPER bound on the
        // true K-th distance (merge selected from a subset of candidates), so a
        // FIXED-threshold filter passes ~K+eps candidates total -> ~K pops.
        const float tau = bd[K - 1];
#pragma unroll
        for (int r = 0; r < K; ++r) { bd[r] = BIGF; bi[r] = 0; }
#pragma unroll 4
        for (int base = 0; base < N_PTS; base += 64) {
            const int j = base + lane;
            float4 p = cand[j];
            float dx = p.x - qx, dy = p.y - qy, dz = p.z - qz;
            float d = dx * dx + dy * dy + dz * dz;
            unsigned long long m = __ballot(d <= tau);
            while (m) {
                int b = __builtin_ctzll(m);
                m &= m - 1;
                float dv = __shfl(d, b);
                if (dv < bd[K - 1]) uinsert<K>(dv, base + b, bd, bi);
            }
        }
    }
}

// ---- kernel 0: build pc2/warp (AoS + packed float4), zero accumulators ----
__global__ void prep_kernel(const float* __restrict__ flow, const float* __restrict__ gt,
                            const float* __restrict__ coords,
                            float* __restrict__ pc2, float* __restrict__ warp,
                            float4* __restrict__ p1q, float4* __restrict__ p2q,
                            float4* __restrict__ wq, float* __restrict__ accs) {
    int i = blockIdx.x * blockDim.x + threadIdx.x;
    if (i < N_PTS) {
        float cx = coords[3 * i + 0], cy = coords[3 * i + 1], cz = coords[3 * i + 2];
        float p2x = cx + gt[3 * i + 0], p2y = cy + gt[3 * i + 1], p2z = cz + gt[3 * i + 2];
        float wx = cx + flow[3 * i + 0], wy = cy + flow[3 * i + 1], wz = cz + flow[3 * i + 2];
        pc2[3 * i + 0] = p2x; pc2[3 * i + 1] = p2y; pc2[3 * i + 2] = p2z;
        warp[3 * i + 0] = wx; warp[3 * i + 1] = wy; warp[3 * i + 2] = wz;
        p1q[i] = make_float4(cx, cy, cz, 0.f);
        p2q[i] = make_float4(p2x, p2y, p2z, 0.f);
        wq[i]  = make_float4(wx, wy, wz, 0.f);
    }
    if (i < 8) accs[i] = 0.0f;
}

// ---- kernel 1: curvature of pc2 via kNN(pc2,pc2,10) ----
__global__ __launch_bounds__(256) void curv2_kernel(const float4* __restrict__ p2q,
                                                    float* __restrict__ curv2) {
    const int tid = threadIdx.x, lane = tid & 63, wv = tid >> 6;
    const int q = blockIdx.x * QPB + wv;
    float4 qp = p2q[q];
    const float qx = qp.x, qy = qp.y, qz = qp.z;
    constexpr int K = 10;
    float bd[K]; int bi[K];
    knn_scan<K>(p2q, qx, qy, qz, bd, bi, lane);
    float ax = 0.f, ay = 0.f, az = 0.f;
#pragma unroll
    for (int r = 0; r < K; ++r) {
        float4 nb = p2q[bi[r]];
        ax += nb.x; ay += nb.y; az += nb.z;
    }
    if (lane == 0) {
        curv2[q * 3 + 0] = (ax - 10.f * qx) * (1.f / 9.f);
        curv2[q * 3 + 1] = (ay - 10.f * qy) * (1.f / 9.f);
        curv2[q * 3 + 2] = (az - 10.f * qz) * (1.f / 9.f);
    }
}

// ---- kernel 2: kNN(pc1,pc1,10) -> moved_curv + smoothness ----
__global__ __launch_bounds__(256) void pc1_kernel(const float4* __restrict__ p1q,
                                                  const float4* __restrict__ wq,
                                                  const float* __restrict__ flow,
                                                  const int* __restrict__ ksm_p,
                                                  float* __restrict__ mcurv,
                                                  float* __restrict__ accs) {
    __shared__ float psm[QPB];
    const int tid = threadIdx.x, lane = tid & 63, wv = tid >> 6;
    const int q = blockIdx.x * QPB + wv;
    float4 qp = p1q[q];
    const float qx = qp.x, qy = qp.y, qz = qp.z;
    constexpr int K = 10;
    float bd[K]; int bi[K];
    knn_scan<K>(p1q, qx, qy, qz, bd, bi, lane);

    float4 wqp = wq[q];
    const float fqx = flow[q * 3 + 0], fqy = flow[q * 3 + 1], fqz = flow[q * 3 + 2];
    const int ksm = ksm_p[0];  // 9
    float ax = 0.f, ay = 0.f, az = 0.f, sm = 0.f;
#pragma unroll
    for (int r = 0; r < K; ++r) {
        float4 nb = wq[bi[r]];
        ax += nb.x; ay += nb.y; az += nb.z;
        if (r < ksm) {
            float dx = flow[bi[r] * 3 + 0] - fqx;
            float dy = flow[bi[r] * 3 + 1] - fqy;
            float dz = flow[bi[r] * 3 + 2] - fqz;
            float sq = dx * dx + dy * dy + dz * dz;
            sm += (sq == 0.f) ? 0.f : sqrtf(sq);
        }
    }
    if (lane == 0) {
        mcurv[q * 3 + 0] = (ax - 10.f * wqp.x) * (1.f / 9.f);
        mcurv[q * 3 + 1] = (ay - 10.f * wqp.y) * (1.f / 9.f);
        mcurv[q * 3 + 2] = (az - 10.f * wqp.z) * (1.f / 9.f);
        psm[wv] = sm * 0.125f;  // /8.0 hard-coded in reference
    }
    __syncthreads();
    if (tid == 0) atomicAdd(&accs[2], psm[0] + psm[1] + psm[2] + psm[3]);
}

// ---- kernel 3: kNN(warp->pc2,5) -> chamfer dist1 + curvature-interp loss ----
__global__ __launch_bounds__(256) void cross_kernel(const float4* __restrict__ wq,
                                                    const float4* __restrict__ p2q,
                                                    const float* __restrict__ curv2,
                                                    const float* __restrict__ mcurv,
                                                    float* __restrict__ accs) {
    __shared__ float pc1s[QPB], pcvs[QPB];
    const int tid = threadIdx.x, lane = tid & 63, wv = tid >> 6;
    const int q = blockIdx.x * QPB + wv;
    float4 qp = wq[q];
    const float qx = qp.x, qy = qp.y, qz = qp.z;
    constexpr int K = 5;
    float bd[K]; int bi[K];
    knn_scan<K>(p2q, qx, qy, qz, bd, bi, lane);

    float w[K], wsum = 0.f;
#pragma unroll
    for (int r = 0; r < K; ++r) { w[r] = 1.f / (bd[r] + 1e-8f); wsum += w[r]; }
    float ix = 0.f, iy = 0.f, iz = 0.f;
#pragma unroll
    for (int r = 0; r < K; ++r) {
        float ww = w[r] / wsum;
        ix += ww * curv2[bi[r] * 3 + 0];
        iy += ww * curv2[bi[r] * 3 + 1];
        iz += ww * curv2[bi[r] * 3 + 2];
    }
    float dx = ix - mcurv[q * 3 + 0];
    float dy = iy - mcurv[q * 3 + 1];
    float dz = iz - mcurv[q * 3 + 2];
    if (lane == 0) {
        pc1s[wv] = bd[0];                       // dist1 (min)
        pcvs[wv] = dx * dx + dy * dy + dz * dz; // curvature term
    }
    __syncthreads();
    if (tid == 0) {
        atomicAdd(&accs[0], pc1s[0] + pc1s[1] + pc1s[2] + pc1s[3]);
        atomicAdd(&accs[3], pcvs[0] + pcvs[1] + pcvs[2] + pcvs[3]);
    }
}

// ---- kernel 4: reverse chamfer: min over warp for each pc2 point ----
__global__ __launch_bounds__(256) void rev_kernel(const float4* __restrict__ p2q,
                                                  const float4* __restrict__ wq,
                                                  float* __restrict__ accs) {
    __shared__ float pmn[QPB];
    const int tid = threadIdx.x, lane = tid & 63, wv = tid >> 6;
    const int q = blockIdx.x * QPB + wv;
    float4 qp = p2q[q];
    const float qx = qp.x, qy = qp.y, qz = qp.z;
    float mny = BIGF;
#pragma unroll 8
    for (int base = 0; base < N_PTS; base += 64) {
        float4 p = wq[base + lane];
        float dx = p.x - qx, dy = p.y - qy, dz = p.z - qz;
        mny = fminf(mny, dx * dx + dy * dy + dz * dz);
    }
#pragma unroll
    for (int off = 1; off < 64; off <<= 1) mny = fminf(mny, __shfl_xor(mny, off));
    if (lane == 0) pmn[wv] = mny;
    __syncthreads();
    if (tid == 0) atomicAdd(&accs[1], pmn[0] + pmn[1] + pmn[2] + pmn[3]);
}

// ---- kernel 5: finalize ----
__global__ void fin_kernel(const float* __restrict__ accs, float* __restrict__ out) {
    if (threadIdx.x == 0 && blockIdx.x == 0)
        out[0] = W_CHAM * (accs[0] + accs[1]) + W_CURV * accs[3] + W_SMOO * accs[2];
}

extern "C" void kernel_launch(void* const* d_in, const int* in_sizes, int n_in,
                              void* d_out, int out_size, void* d_ws, size_t ws_size,
                              hipStream_t stream) {
    const float* flow   = (const float*)d_in[0];  // registration_pred (1,N,3)
    const float* gt     = (const float*)d_in[1];  // registration_gt   (1,N,3)
    const float* coords = (const float*)d_in[2];  // (N,3)
    const int*   ksm    = (const int*)d_in[3];    // smoothness_k (=9)

    float* ws    = (float*)d_ws;
    float* pc2   = ws;                 // 3N
    float* warp  = ws + 3 * N_PTS;     // 3N
    float* curv2 = ws + 6 * N_PTS;     // 3N
    float* mcurv = ws + 9 * N_PTS;     // 3N
    float* accs  = ws + 12 * N_PTS;    // 8 floats (offset 98304)
    float4* p1q  = (float4*)(ws + 12 * N_PTS + 8);   // N float4 (16B-aligned)
    float4* p2q  = p1q + N_PTS;
    float4* wq   = p2q + N_PTS;
    float* out   = (float*)d_out;

    prep_kernel<<<(N_PTS + 255) / 256, 256, 0, stream>>>(flow, gt, coords, pc2, warp,
                                                         p1q, p2q, wq, accs);
    curv2_kernel<<<N_PTS / QPB, 256, 0, stream>>>(p2q, curv2);
    pc1_kernel<<<N_PTS / QPB, 256, 0, stream>>>(p1q, wq, flow, ksm, mcurv, accs);
    cross_kernel<<<N_PTS / QPB, 256, 0, stream>>>(wq, p2q, curv2, mcurv, accs);
    rev_kernel<<<N_PTS / QPB, 256, 0, stream>>>(p2q, wq, accs);
    fin_kernel<<<1, 64, 0, stream>>>(accs, out);
}